// Round 6
// baseline (141.126 us; speedup 1.0000x reference)
//
#include <hip/hip_runtime.h>
#include <hip/hip_bf16.h>

// Word2MatEncoder: out[b] = prod_{t=0..63} lookup_weight[sent[b,t]] (28x28 chain)
//
// Kernel 1 (w2m_partial_mfma): 4096 one-wave blocks (256 batch x 16 seg, 4
//   matrices per segment). R_t = R_{t-1} * M_t via v_mfma_f32_32x32x16_bf16,
//   f32 emulated by exact truncation split x = hi + lo (3 cross terms x 2
//   K-halves = 6 MFMA/step).
//   VERIFIED (R4/R5, absmax 32): A/B layout m,n = lane&31, k = 8*(lane>>5)+e;
//   C/D layout col = lane&31, row = (reg&3)+8*(reg>>2)+4*(lane>>5).
//   R5 was latency-bound at 2 waves/EU (pinned) with an 8-step serial chain
//   (~22us vs ~6.5us LDS-issue floor). This round:
//     - SEG 8->16: 16 blocks/CU, 4 waves/EU (waves_per_eu(3,4); ~100 live
//       VGPR < 128), serial chain halved to 4 steps.
//     - Zero-tail Ms[1024] (tail zeroed once): B pad ROWS (k>=28) read exact
//       zeros, which nullifies all pad garbage (A pad cols hit zero B rows;
//       D pad rows/cols masked at the final store) -> NO per-step bounds
//       checks (-32 VALU/step). Staging publish stays conflict-free b128.
//     - RL pitch 33: relayout writes RL[r][n] banks (r+n)%32 and reads
//       RL[m][k] banks (m+k)%32 both conflict-free scalar b32.
//
// Kernel 2 (w2m_combine): verified R2 structure extended to 16 partials:
//   512 threads (8 waves), 4 tree levels. Parity convention per level:
//   even index stored transposed (A-side), odd row-major (B-side).

typedef float f32x4  __attribute__((ext_vector_type(4)));
typedef float f32x16 __attribute__((ext_vector_type(16)));
typedef short bf16x8 __attribute__((ext_vector_type(8)));

namespace {
constexpr int MD  = 28;
constexpr int EMB = 784;
constexpr int SEQ = 64;
constexpr int BATCH = 256;
constexpr int SEG = 16;  // segments per batch
constexpr int LEN = 4;   // matrices per segment
constexpr int RLP = 33;  // RL pitch (floats): banks (r+n)%32, conflict-free
}

__device__ __forceinline__ bf16x8 mkfrag(uint32_t w0, uint32_t w1,
                                         uint32_t w2, uint32_t w3) {
  union { uint32_t w[4]; bf16x8 b; } u;
  u.w[0] = w0; u.w[1] = w1; u.w[2] = w2; u.w[3] = w3;
  return u.b;
}

// 8 f32 -> hi/lo bf16 fragments. Truncation split: hi = x & 0xffff0000 (exact
// bf16), lo = x - hi (exact), lo truncated to bf16.
__device__ __forceinline__ void split8(const float* x, bf16x8& hi, bf16x8& lo) {
  uint32_t H[4], L[4];
#pragma unroll
  for (int p = 0; p < 4; ++p) {
    float x0 = x[2 * p], x1 = x[2 * p + 1];
    uint32_t h0 = __float_as_uint(x0) & 0xffff0000u;
    uint32_t h1 = __float_as_uint(x1) & 0xffff0000u;
    float l0 = x0 - __uint_as_float(h0);
    float l1 = x1 - __uint_as_float(h1);
    H[p] = (h0 >> 16) | h1;
    L[p] = (__float_as_uint(l0) >> 16) | (__float_as_uint(l1) & 0xffff0000u);
  }
  hi = mkfrag(H[0], H[1], H[2], H[3]);
  lo = mkfrag(L[0], L[1], L[2], L[3]);
}

__global__ __launch_bounds__(64)
__attribute__((amdgpu_waves_per_eu(3, 4)))
void w2m_partial_mfma(const int* __restrict__ sent,
                      const float* __restrict__ W,
                      float* __restrict__ ws) {
  __shared__ __align__(16) float Ms[1024];      // M_t linear + zero tail
  __shared__ __align__(16) float RL[32 * RLP];  // D -> A relayout buffer

  const int blk   = blockIdx.x;
  const int batch = blk >> 4;
  const int seg   = blk & 15;
  const int lane  = threadIdx.x;
  const int n = lane & 31;          // A-row m / B-col n / D-col
  const int h = lane >> 5;
  const int* srow = sent + batch * SEQ + seg * LEN;

  // Zero tail [784, 1024): 60 f32x4 chunks. B rows k>=28 then read zeros.
  if (lane < 60) *reinterpret_cast<f32x4*>(&Ms[784 + 4 * lane]) =
      (f32x4){0.f, 0.f, 0.f, 0.f};

  // Coalesced gather of one 28x28 matrix into a 4-register stage.
  f32x4 st0, st1, st2, st3;
  auto gstage = [&](int t) {
    const f32x4* src = reinterpret_cast<const f32x4*>(W + (size_t)srow[t] * EMB);
    st0 = src[lane];
    st1 = src[64 + lane];
    st2 = src[128 + lane];
    if (lane < 4) st3 = src[192 + lane];   // 784 = 3*256 + 16
  };
  auto lpublish = [&]() {
    f32x4* d_ = reinterpret_cast<f32x4*>(Ms);
    d_[lane] = st0;
    d_[64 + lane] = st1;
    d_[128 + lane] = st2;
    if (lane < 4) d_[192 + lane] = st3;
  };

  // A fragments of M0, direct from global (row-contiguous; bounds-checked:
  // keeps last-table-row reads in bounds and pads with zeros).
  float a[16];
  {
    const float* __restrict__ M0 = W + (size_t)srow[0] * EMB;
    const int m = n;
#pragma unroll
    for (int K = 0; K < 2; ++K)
#pragma unroll
      for (int u = 0; u < 2; ++u) {
        int k0 = 16 * K + 8 * h + 4 * u;
        f32x4 v = {0.f, 0.f, 0.f, 0.f};
        if (m < MD && k0 < MD)
          v = *reinterpret_cast<const f32x4*>(M0 + m * MD + k0);
        a[K * 8 + 4 * u + 0] = v[0];
        a[K * 8 + 4 * u + 1] = v[1];
        a[K * 8 + 4 * u + 2] = v[2];
        a[K * 8 + 4 * u + 3] = v[3];
      }
  }

  // Prologue: M1 -> Ms; prefetch M2 into stage regs.
  gstage(1);
  lpublish();
  gstage(2);

  f32x16 d;
#pragma unroll
  for (int t = 1; t < LEN; ++t) {
    // B fragments of M_t from LDS, NO bounds checks (zero tail covers k>=28;
    // n>=28 garbage is finite and nullified downstream).
    // Banks: (28k+n)%32; h=0/h=1 differ by 224 ≡ 0 (mod 32) -> exactly
    // 2 lanes/bank (different addrs) = free.
    float bb[16];
#pragma unroll
    for (int K = 0; K < 2; ++K)
#pragma unroll
      for (int e = 0; e < 8; ++e) {
        int k = 16 * K + 8 * h + e;
        bb[K * 8 + e] = Ms[k * MD + n];
      }

    bf16x8 ah0, al0, ah1, al1, bh0, bl0, bh1, bl1;
    split8(a,      ah0, al0);
    split8(a + 8,  ah1, al1);
    split8(bb,     bh0, bl0);
    split8(bb + 8, bh1, bl1);

#pragma unroll
    for (int q = 0; q < 16; ++q) d[q] = 0.f;
    d = __builtin_amdgcn_mfma_f32_32x32x16_bf16(ah0, bh0, d, 0, 0, 0);
    d = __builtin_amdgcn_mfma_f32_32x32x16_bf16(ah0, bl0, d, 0, 0, 0);
    d = __builtin_amdgcn_mfma_f32_32x32x16_bf16(al0, bh0, d, 0, 0, 0);
    d = __builtin_amdgcn_mfma_f32_32x32x16_bf16(ah1, bh1, d, 0, 0, 0);
    d = __builtin_amdgcn_mfma_f32_32x32x16_bf16(ah1, bl1, d, 0, 0, 0);
    d = __builtin_amdgcn_mfma_f32_32x32x16_bf16(al1, bh1, d, 0, 0, 0);

    if (t < LEN - 1) {
      lpublish();                       // publish M_{t+1} (in-order LDS: after
      if (t + 2 < LEN) gstage(t + 2);   //   this step's bb reads)

      // D -> RL (row-major) -> A fragments. Single wave: no barrier.
      // Writes RL[r][n]: banks (r+n)%32 conflict-free; reads RL[m][k]:
      // banks (m+k)%32 conflict-free.
#pragma unroll
      for (int e = 0; e < 16; ++e) {
        int r = (e & 3) + 8 * (e >> 2) + 4 * h;
        RL[r * RLP + n] = d[e];
      }
      const int m = n;
#pragma unroll
      for (int K = 0; K < 2; ++K)
#pragma unroll
        for (int e = 0; e < 8; ++e) {
          int k = 16 * K + 8 * h + e;
          a[K * 8 + e] = RL[m * RLP + k];
        }
    }
  }

  // D = P (segment product). even seg: store P^T (A-side, vectorized);
  // odd seg: store P row-major (B-side). Pad rows/cols masked out.
  float* pb = ws + (size_t)(batch * SEG + seg) * EMB;
  if (n < MD) {
    if ((seg & 1) == 0) {
#pragma unroll
      for (int q = 0; q < 4; ++q) {
        int rbase = 8 * q + 4 * h;
        if (rbase < MD) {
          f32x4 v = { d[4 * q], d[4 * q + 1], d[4 * q + 2], d[4 * q + 3] };
          *reinterpret_cast<f32x4*>(pb + n * MD + rbase) = v;
        }
      }
    } else {
#pragma unroll
      for (int e = 0; e < 16; ++e) {
        int r = (e & 3) + 8 * (e >> 2) + 4 * h;
        if (r < MD) pb[r * MD + n] = d[e];
      }
    }
  }
}

// ---------------- kernel 2: tree-combine 16 partials ----------------

__device__ __forceinline__ void kloop(const float* __restrict__ A,
                                      const float* __restrict__ B,
                                      int r0, int c0,
                                      f32x4& a0, f32x4& a1, f32x4& a2, f32x4& a3) {
  f32x4 z = {0.f, 0.f, 0.f, 0.f};
  a0 = a1 = a2 = a3 = z;
#pragma unroll
  for (int k = 0; k < MD; ++k) {
    f32x4 rv = *reinterpret_cast<const f32x4*>(A + k * MD + r0);
    f32x4 mv = *reinterpret_cast<const f32x4*>(B + k * MD + c0);
    a0 += rv[0] * mv;
    a1 += rv[1] * mv;
    a2 += rv[2] * mv;
    a3 += rv[3] * mv;
  }
}

__device__ __forceinline__ void store_T(float* __restrict__ D, int r0, int c0,
                                        const f32x4& a0, const f32x4& a1,
                                        const f32x4& a2, const f32x4& a3) {
#pragma unroll
  for (int cc = 0; cc < 4; ++cc) {
    f32x4 v = { a0[cc], a1[cc], a2[cc], a3[cc] };
    *reinterpret_cast<f32x4*>(D + (c0 + cc) * MD + r0) = v;
  }
}

__device__ __forceinline__ void store_N(float* __restrict__ D, int r0, int c0,
                                        const f32x4& a0, const f32x4& a1,
                                        const f32x4& a2, const f32x4& a3) {
  *reinterpret_cast<f32x4*>(D + (r0 + 0) * MD + c0) = a0;
  *reinterpret_cast<f32x4*>(D + (r0 + 1) * MD + c0) = a1;
  *reinterpret_cast<f32x4*>(D + (r0 + 2) * MD + c0) = a2;
  *reinterpret_cast<f32x4*>(D + (r0 + 3) * MD + c0) = a3;
}

__global__ __launch_bounds__(512, 1)
void w2m_combine(const float* __restrict__ ws, float* __restrict__ out) {
  __shared__ __align__(16) float P[SEG][EMB];   // 49 KB
  __shared__ __align__(16) float Q8[8][EMB];    // 24.5 KB
  __shared__ __align__(16) float Q4[4][EMB];    // 12.25 KB
  __shared__ __align__(16) float Q2[2][EMB];    // 6.1 KB

  const int batch = blockIdx.x;
  const int tid   = threadIdx.x;
  const int w     = tid >> 6;       // 0..7
  const int lane  = tid & 63;
  const bool act  = lane < 49;
  const int i = lane / 7, j = lane % 7;
  const int r0 = 4 * i, c0 = 4 * j;

  {
    const f32x4* src = reinterpret_cast<const f32x4*>(ws + (size_t)batch * SEG * EMB);
    f32x4* dst = reinterpret_cast<f32x4*>(&P[0][0]);
    for (int u = tid; u < SEG * EMB / 4; u += 512) dst[u] = src[u];
  }
  __syncthreads();

  f32x4 a0, a1, a2, a3;
  // level 0: Q8[w] = P[2w] * P[2w+1]   (8 waves)
  if (act) {
    kloop(P[2 * w], P[2 * w + 1], r0, c0, a0, a1, a2, a3);
    if (w & 1) store_N(Q8[w], r0, c0, a0, a1, a2, a3);
    else       store_T(Q8[w], r0, c0, a0, a1, a2, a3);
  }
  __syncthreads();
  // level 1: Q4[w] = Q8[2w] * Q8[2w+1]  (4 waves)
  if (w < 4 && act) {
    kloop(Q8[2 * w], Q8[2 * w + 1], r0, c0, a0, a1, a2, a3);
    if (w & 1) store_N(Q4[w], r0, c0, a0, a1, a2, a3);
    else       store_T(Q4[w], r0, c0, a0, a1, a2, a3);
  }
  __syncthreads();
  // level 2: Q2[w] = Q4[2w] * Q4[2w+1]  (2 waves)
  if (w < 2 && act) {
    kloop(Q4[2 * w], Q4[2 * w + 1], r0, c0, a0, a1, a2, a3);
    if (w & 1) store_N(Q2[w], r0, c0, a0, a1, a2, a3);
    else       store_T(Q2[w], r0, c0, a0, a1, a2, a3);
  }
  __syncthreads();
  // level 3: out = Q2[0] * Q2[1]
  if (w == 0 && act) {
    kloop(Q2[0], Q2[1], r0, c0, a0, a1, a2, a3);
    store_N(out + (size_t)batch * EMB, r0, c0, a0, a1, a2, a3);
  }
}

extern "C" void kernel_launch(void* const* d_in, const int* in_sizes, int n_in,
                              void* d_out, int out_size, void* d_ws, size_t ws_size,
                              hipStream_t stream) {
  const int*   sent = (const int*)d_in[0];    // (256, 64) int32
  const float* W    = (const float*)d_in[1];  // (30001, 784) f32
  float*       out  = (float*)d_out;          // (256, 784) f32
  float*       ws   = (float*)d_ws;           // 256*16*784*4 = 12.8 MB
  (void)in_sizes; (void)n_in; (void)out_size; (void)ws_size;

  w2m_partial_mfma<<<BATCH * SEG, 64, 0, stream>>>(sent, W, ws);
  w2m_combine<<<BATCH, 512, 0, stream>>>(ws, out);
}